// Round 12
// baseline (14466.270 us; speedup 1.0000x reference)
//
#include <hip/hip_runtime.h>
#include <hip/hip_cooperative_groups.h>
#include <cmath>

namespace cg = cooperative_groups;

#define NALL 3072
#define NF   3056
#define NT   3056
#define NC4  764          // NT/4
#define RPB  8            // rows per block
#define NBLK (NF/RPB)     // 382 blocks
#define SPLIT 32          // fallback colsum slices
#define RPS  ((NBLK + SPLIT - 1) / SPLIT)
#define TPB  256
#define LRc  0.1f
#define AEPS 1e-8f
#define OEPS 0.1f
#define ITERS 100

__device__ __forceinline__ float sigf(float x) {
    return 1.0f / (1.0f + __expf(-x));
}

// ---- bf16 helpers: 4 elems <-> uint2 (8B), RTN-even rounding ----
__device__ __forceinline__ unsigned int pkbf(float x) {
    unsigned int t = __float_as_uint(x);
    return (t + 0x7FFFu + ((t >> 16) & 1u)) >> 16;
}
__device__ __forceinline__ float4 ld_bf4(const unsigned short* p) {
    uint2 u = *(const uint2*)p;
    float4 r;
    r.x = __uint_as_float(u.x << 16);
    r.y = __uint_as_float(u.x & 0xFFFF0000u);
    r.z = __uint_as_float(u.y << 16);
    r.w = __uint_as_float(u.y & 0xFFFF0000u);
    return r;
}
__device__ __forceinline__ void st_bf4(unsigned short* p, float4 v) {
    uint2 u;
    u.x = pkbf(v.x) | (pkbf(v.y) << 16);
    u.y = pkbf(v.z) | (pkbf(v.w) << 16);
    *(uint2*)p = u;
}

// ---------------- one-time cast of A[:NF, 16:] block to bf16 ----------------
__global__ void __launch_bounds__(TPB)
castA_kernel(const float* __restrict__ A, unsigned short* __restrict__ Abf)
{
    const int tid = threadIdx.x;
    const bool ok2 = tid < (NC4 - 512);
    const int i = blockIdx.x;
    const size_t abase = (size_t)i * NALL + 16;
    const size_t obase = (size_t)i * NT;
    #pragma unroll
    for (int k = 0; k < 3; ++k) {
        if (k == 2 && !ok2) continue;
        const int c4 = tid + 256*k;
        float4 a = *(const float4*)(A + abase + 4*c4);
        st_bf4(Abf + obase + 4*c4, a);
    }
}

// ======== shared step-phase body (device inline), used by both paths ========
template<bool FIRST>
__device__ __forceinline__ void step_rows(
    int b, const float* __restrict__ GL_init,
    unsigned short* __restrict__ GLbf, unsigned short* __restrict__ mG,
    unsigned short* __restrict__ vG, const unsigned short* __restrict__ Abf,
    const float* __restrict__ tau, float* __restrict__ Srow,
    float* __restrict__ Pcol, float bc1i, float bc2i,
    float* red /*shared[8]*/)
{
    const int tid  = threadIdx.x;
    const int lane = tid & 63;
    const int wv   = tid >> 6;
    const bool ok2 = tid < (NC4 - 512);
    const float c1 = 0.5f / (float)NF;
    const float c2 = 0.5f / ((float)NF * (float)NT);

    float4 tv[3];
    tv[0] = *(const float4*)(tau + 16 + 4 * tid);
    tv[1] = *(const float4*)(tau + 16 + 4 * (tid + 256));
    tv[2] = ok2 ? *(const float4*)(tau + 16 + 4 * (tid + 512)) : make_float4(0.f,0.f,0.f,0.f);

    float4 cacc[3];
    #pragma unroll
    for (int k = 0; k < 3; ++k) cacc[k] = make_float4(0.f,0.f,0.f,0.f);

    for (int rr = 0; rr < RPB; ++rr) {
        const int i = b * RPB + rr;
        const float tu = tau[i];
        const size_t g4base = (size_t)i * NC4;

        float4 gl[3], a4[3], m4[3], v4[3];
        #pragma unroll
        for (int k = 0; k < 3; ++k) {
            if (k == 2 && !ok2) continue;
            const int c4 = tid + 256*k;
            const size_t e = 4*(g4base + c4);
            gl[k] = FIRST ? ((const float4*)GL_init)[g4base + c4] : ld_bf4(GLbf + e);
            a4[k] = ld_bf4(Abf + e);
            if (FIRST) { m4[k] = make_float4(0.f,0.f,0.f,0.f); v4[k] = m4[k]; }
            else { m4[k] = ld_bf4(mG + e); v4[k] = ld_bf4(vG + e); }
        }

        float4 G4[3];
        float pl = 1.0f;
        #pragma unroll
        for (int k = 0; k < 3; ++k) {
            if (k == 2 && !ok2) continue;
            float4 g;
            g.x = sigf(gl[k].x); g.y = sigf(gl[k].y);
            g.z = sigf(gl[k].z); g.w = sigf(gl[k].w);
            G4[k] = g;
            pl *= fmaf(-2.0f*a4[k].x, g.x, 1.0f);
            pl *= fmaf(-2.0f*a4[k].y, g.y, 1.0f);
            pl *= fmaf(-2.0f*a4[k].z, g.z, 1.0f);
            pl *= fmaf(-2.0f*a4[k].w, g.w, 1.0f);
        }
        float pw = pl;
        #pragma unroll
        for (int off = 1; off < 64; off <<= 1) pw *= __shfl_xor(pw, off, 64);
        __syncthreads();
        if (lane == 0) red[wv] = pw;
        __syncthreads();
        const float p = red[0]*red[1]*red[2]*red[3];
        const float c1pp = c1 * (p + 1.0f);
        const bool pzero = (p == 0.0f);   // block-uniform

        float rowl = 0.0f;
        #pragma unroll
        for (int k = 0; k < 3; ++k) {
            if (k == 2 && !ok2) continue;
            const int c4 = tid + 256*k;
            const size_t e = 4*(g4base + c4);
            float4 glo, mo, vo;
            if (pzero) {
                #define COMPF(FLD) { \
                    const float g = G4[k].FLD; \
                    const float d = tu - tv[k].FLD + OEPS; \
                    const float r = fmaxf(d, 0.0f); \
                    const float gg = (c2 * (r*r)) * (g * (1.0f - g)); \
                    const float m2 = fmaf(0.9f, m4[k].FLD, 0.1f*gg); \
                    const float v2 = fmaf(0.999f, v4[k].FLD, 0.001f*gg*gg); \
                    const float den = __fsqrt_rn(v2 * bc2i) + AEPS; \
                    glo.FLD = gl[k].FLD - LRc * (m2 * bc1i) / den; \
                    mo.FLD = m2; vo.FLD = v2; \
                    const float w = g * r; \
                    rowl += w; cacc[k].FLD += w; }
                COMPF(x) COMPF(y) COMPF(z) COMPF(w)
                #undef COMPF
            } else {
                #define COMP(FLD) { \
                    const float g = G4[k].FLD; \
                    const float a = a4[k].FLD; \
                    const float f = fmaf(-2.0f*a, g, 1.0f); \
                    const float po = (f != 0.0f) ? __fdividef(p, f) : 0.0f; \
                    const float d = tu - tv[k].FLD + OEPS; \
                    const float r = fmaxf(d, 0.0f); \
                    const float gg = fmaf(c2, r*r, c1pp * po * (-2.0f*a)) * (g * (1.0f - g)); \
                    const float m2 = fmaf(0.9f, m4[k].FLD, 0.1f*gg); \
                    const float v2 = fmaf(0.999f, v4[k].FLD, 0.001f*gg*gg); \
                    const float den = __fsqrt_rn(v2 * bc2i) + AEPS; \
                    glo.FLD = gl[k].FLD - LRc * (m2 * bc1i) / den; \
                    mo.FLD = m2; vo.FLD = v2; \
                    const float w = g * r; \
                    rowl += w; cacc[k].FLD += w; }
                COMP(x) COMP(y) COMP(z) COMP(w)
                #undef COMP
            }
            st_bf4(GLbf + e, glo);
            st_bf4(mG + e, mo);
            st_bf4(vG + e, vo);
        }

        float sw = rowl;
        #pragma unroll
        for (int off = 1; off < 64; off <<= 1) sw += __shfl_xor(sw, off, 64);
        if (lane == 0) red[4+wv] = sw;
        __syncthreads();
        if (tid == 0) Srow[i] = (red[4]+red[5]) + (red[6]+red[7]);
    }

    float* pc = Pcol + (size_t)b * NT;
    #pragma unroll
    for (int k = 0; k < 3; ++k) {
        if (k == 2 && !ok2) continue;
        *(float4*)(pc + 4*(tid + 256*k)) = cacc[k];
    }
}

// ---------------- cooperative mega-kernel ----------------
__global__ void __launch_bounds__(TPB, 4)
mega_kernel(const float* __restrict__ A, const float* __restrict__ tau_init,
            const float* __restrict__ GL_init,
            unsigned short* __restrict__ GLbf, unsigned short* __restrict__ mG,
            unsigned short* __restrict__ vG, const unsigned short* __restrict__ Abf,
            float* __restrict__ tauw, float* __restrict__ mt, float* __restrict__ vt,
            float* __restrict__ Srow, float* __restrict__ Pcol, float* __restrict__ out)
{
    cg::grid_group grid = cg::this_grid();
    __shared__ float red[8];
    __shared__ float redc[32];
    const int tid  = threadIdx.x;
    const int lane = tid & 63;
    const int wv   = tid >> 6;
    const bool ok2 = tid < (NC4 - 512);
    const int b    = blockIdx.x;
    const float ct = 1.0f / ((float)NF * (float)NT);

    double b1p = 1.0, b2p = 1.0;
    for (int it = 0; it < ITERS; ++it) {
        b1p *= 0.9; b2p *= 0.999;
        const float bc1i = (float)(1.0 / (1.0 - b1p));
        const float bc2i = (float)(1.0 / (1.0 - b2p));

        if (it == 0)
            step_rows<true >(b, GL_init, GLbf, mG, vG, Abf, tau_init, Srow, Pcol, bc1i, bc2i, red);
        else
            step_rows<false>(b, nullptr,  GLbf, mG, vG, Abf, tauw,     Srow, Pcol, bc1i, bc2i, red);

        grid.sync();

        // block b reduces columns 8b..8b+7 and Adam-updates tau[8b+16..8b+23]
        {
            float4 a0 = make_float4(0.f,0.f,0.f,0.f);
            float4 a1 = make_float4(0.f,0.f,0.f,0.f);
            const float* pp = Pcol + 8*b;
            for (int r = tid; r < NBLK; r += TPB) {
                float4 v0 = *(const float4*)(pp + (size_t)r * NT);
                float4 v1 = *(const float4*)(pp + (size_t)r * NT + 4);
                a0.x += v0.x; a0.y += v0.y; a0.z += v0.z; a0.w += v0.w;
                a1.x += v1.x; a1.y += v1.y; a1.z += v1.z; a1.w += v1.w;
            }
            #pragma unroll
            for (int off = 1; off < 64; off <<= 1) {
                a0.x += __shfl_xor(a0.x, off, 64);
                a0.y += __shfl_xor(a0.y, off, 64);
                a0.z += __shfl_xor(a0.z, off, 64);
                a0.w += __shfl_xor(a0.w, off, 64);
                a1.x += __shfl_xor(a1.x, off, 64);
                a1.y += __shfl_xor(a1.y, off, 64);
                a1.z += __shfl_xor(a1.z, off, 64);
                a1.w += __shfl_xor(a1.w, off, 64);
            }
            if (lane == 0) {
                redc[wv*8+0] = a0.x; redc[wv*8+1] = a0.y;
                redc[wv*8+2] = a0.z; redc[wv*8+3] = a0.w;
                redc[wv*8+4] = a1.x; redc[wv*8+5] = a1.y;
                redc[wv*8+6] = a1.z; redc[wv*8+7] = a1.w;
            }
            __syncthreads();
            if (tid < 8) {
                const float cs = (redc[tid] + redc[8+tid]) + (redc[16+tid] + redc[24+tid]);
                const int k = 8*b + 16 + tid;
                float g = (((k < NF) ? Srow[k] : 0.0f) - cs) * ct;
                const float t0 = (it == 0) ? tau_init[k] : tauw[k];
                const float m0 = (it == 0) ? 0.0f : mt[k];
                const float v0 = (it == 0) ? 0.0f : vt[k];
                const float m2 = fmaf(0.9f, m0, 0.1f*g);
                const float v2 = fmaf(0.999f, v0, 0.001f*g*g);
                const float den = __fsqrt_rn(v2 * bc2i) + AEPS;
                tauw[k] = t0 - LRc * (m2 * bc1i) / den;
                mt[k] = m2; vt[k] = v2;
            }
            if (b == 0 && tid >= 8 && tid < 24) {
                const int k = tid - 8;        // k = 0..15: row-sum term only
                float g = Srow[k] * ct;
                const float t0 = (it == 0) ? tau_init[k] : tauw[k];
                const float m0 = (it == 0) ? 0.0f : mt[k];
                const float v0 = (it == 0) ? 0.0f : vt[k];
                const float m2 = fmaf(0.9f, m0, 0.1f*g);
                const float v2 = fmaf(0.999f, v0, 0.001f*g*g);
                const float den = __fsqrt_rn(v2 * bc2i) + AEPS;
                tauw[k] = t0 - LRc * (m2 * bc1i) / den;
                mt[k] = m2; vt[k] = v2;
            }
        }
        grid.sync();
    }

    // ======== final loss (original fp32 A, bf16 final GL, final tauw) ========
    float lsum = 0.0f;
    for (int rr = 0; rr < RPB; ++rr) {
        const int i = b * RPB + rr;
        const float tu = tauw[i];
        const size_t g4base = (size_t)i * NC4;
        const size_t abase  = (size_t)i * NALL + 16;
        float pl = 1.0f, sl = 0.0f;
        #pragma unroll
        for (int k = 0; k < 3; ++k) {
            if (k == 2 && !ok2) continue;
            const int c4 = tid + 256*k;
            float4 gl = ld_bf4(GLbf + 4*(g4base + c4));
            float4 a  = *(const float4*)(A + abase + 4*c4);
            float4 tvv = *(const float4*)(tauw + 16 + 4*c4);
            #define LCOMP(FLD) { \
                const float g = sigf(gl.FLD); \
                pl *= fmaf(-2.0f*a.FLD, g, 1.0f); \
                const float r = fmaxf(tu - tvv.FLD + OEPS, 0.0f); \
                sl += g * r * r; }
            LCOMP(x) LCOMP(y) LCOMP(z) LCOMP(w)
            #undef LCOMP
        }
        float pw = pl, sw = sl;
        #pragma unroll
        for (int off = 1; off < 64; off <<= 1) {
            pw *= __shfl_xor(pw, off, 64);
            sw += __shfl_xor(sw, off, 64);
        }
        __syncthreads();
        if (lane == 0) { red[wv] = pw; red[4+wv] = sw; }
        __syncthreads();
        if (tid == 0) {
            const float p = red[0]*red[1]*red[2]*red[3];
            const float s = (red[4]+red[5]) + (red[6]+red[7]);
            lsum += 0.25f*(p+1.0f)*(p+1.0f)*(1.0f/(float)NF)
                  + 0.5f*s*(1.0f/((float)NF*(float)NT));
        }
    }
    if (tid == 0) atomicAdd(out, lsum);
}

// ================= fallback path (separate kernels, same math) =================
template<bool FIRST>
__global__ void __launch_bounds__(TPB)
step_kernel(const float* GLinit, unsigned short* __restrict__ GLbf,
            unsigned short* __restrict__ mG, unsigned short* __restrict__ vG,
            const unsigned short* __restrict__ Abf, const float* __restrict__ tau,
            float* __restrict__ Srow, float* __restrict__ Pcol,
            float bc1i, float bc2i)
{
    __shared__ float red[8];
    step_rows<FIRST>(blockIdx.x, GLinit, GLbf, mG, vG, Abf, tau, Srow, Pcol, bc1i, bc2i, red);
}

__global__ void __launch_bounds__(TPB)
colsum_kernel(const float* __restrict__ Pcol, float* __restrict__ Pcol2)
{
    const int c = blockIdx.x * TPB + threadIdx.x;
    if (c >= NT) return;
    const int s  = blockIdx.y;
    const int r0 = s * RPS;
    const int r1 = (r0 + RPS < NBLK) ? (r0 + RPS) : NBLK;
    float a[8];
    #pragma unroll
    for (int u = 0; u < 8; ++u) a[u] = 0.0f;
    const float* p = Pcol + (size_t)r0 * NT + c;
    int r = r0;
    for (; r + 8 <= r1; r += 8) {
        #pragma unroll
        for (int u = 0; u < 8; ++u) a[u] += p[(size_t)u * NT];
        p += (size_t)8 * NT;
    }
    for (; r < r1; ++r) { a[0] += *p; p += NT; }
    Pcol2[(size_t)s * NT + c] =
        ((a[0]+a[1])+(a[2]+a[3])) + ((a[4]+a[5])+(a[6]+a[7]));
}

template<bool FIRST>
__global__ void __launch_bounds__(TPB)
tau_kernel(const float* tinit, float* tauw,
           float* __restrict__ mt, float* __restrict__ vt,
           const float* __restrict__ Srow, const float* __restrict__ Pcol2,
           float bc1i, float bc2i)
{
    const int k = blockIdx.x * TPB + threadIdx.x;
    if (k >= NALL) return;
    const float ct = 1.0f / ((float)NF * (float)NT);
    float g = 0.0f;
    if (k < NF) g = Srow[k];
    if (k >= 16) {
        const int j = k - 16;
        float s = 0.0f;
        #pragma unroll
        for (int t = 0; t < SPLIT; ++t) s += Pcol2[(size_t)t * NT + j];
        g -= s;
    }
    g *= ct;
    const float t0 = FIRST ? tinit[k] : tauw[k];
    const float m0 = FIRST ? 0.0f : mt[k];
    const float v0 = FIRST ? 0.0f : vt[k];
    const float m2 = fmaf(0.9f, m0, 0.1f*g);
    const float v2 = fmaf(0.999f, v0, 0.001f*g*g);
    const float den = __fsqrt_rn(v2 * bc2i) + AEPS;
    tauw[k] = t0 - LRc * (m2 * bc1i) / den;
    mt[k] = m2; vt[k] = v2;
}

__global__ void __launch_bounds__(TPB)
loss_kernel(const unsigned short* __restrict__ GLbf, const float* __restrict__ A,
            const float* __restrict__ tau, float* __restrict__ out)
{
    __shared__ float red[8];
    const int tid = threadIdx.x;
    const int lane = tid & 63, wv = tid >> 6;
    const bool ok2 = tid < (NC4 - 512);
    const int i = blockIdx.x;
    const float tu = tau[i];
    const size_t g4base = (size_t)i * NC4;
    const size_t abase  = (size_t)i * NALL + 16;
    float pl = 1.0f, sl = 0.0f;
    #pragma unroll
    for (int k = 0; k < 3; ++k) {
        if (k == 2 && !ok2) continue;
        const int c4 = tid + 256*k;
        float4 gl = ld_bf4(GLbf + 4*(g4base + c4));
        float4 a  = *(const float4*)(A + abase + 4*c4);
        float4 tv = *(const float4*)(tau + 16 + 4*c4);
        #define LCOMP(FLD) { \
            const float g = sigf(gl.FLD); \
            pl *= fmaf(-2.0f*a.FLD, g, 1.0f); \
            const float r = fmaxf(tu - tv.FLD + OEPS, 0.0f); \
            sl += g * r * r; }
        LCOMP(x) LCOMP(y) LCOMP(z) LCOMP(w)
        #undef LCOMP
    }
    float pw = pl, sw = sl;
    #pragma unroll
    for (int off = 1; off < 64; off <<= 1) {
        pw *= __shfl_xor(pw, off, 64);
        sw += __shfl_xor(sw, off, 64);
    }
    if (lane == 0) { red[wv] = pw; red[4+wv] = sw; }
    __syncthreads();
    if (tid == 0) {
        const float p = red[0]*red[1]*red[2]*red[3];
        const float s = (red[4]+red[5]) + (red[6]+red[7]);
        const float v = 0.25f*(p+1.0f)*(p+1.0f)*(1.0f/(float)NF)
                      + 0.5f*s*(1.0f/((float)NF*(float)NT));
        atomicAdd(out, v);
    }
}

// ---------------- host ----------------
extern "C" void kernel_launch(void* const* d_in, const int* in_sizes, int n_in,
                              void* d_out, int out_size, void* d_ws, size_t ws_size,
                              hipStream_t stream)
{
    const float* A        = (const float*)d_in[0];
    const float* tau_init = (const float*)d_in[1];
    const float* GL_init  = (const float*)d_in[2];

    const size_t mat = (size_t)NF * NT;
    unsigned short* GLbf = (unsigned short*)d_ws;         // mat bf16
    unsigned short* mGh  = GLbf + mat;                    // mat bf16
    unsigned short* vGh  = mGh + mat;                     // mat bf16
    unsigned short* Abf  = vGh + mat;                     // mat bf16
    float* tauw  = (float*)(Abf + mat);
    float* mt    = tauw + NALL;
    float* vt    = mt + NALL;
    float* Srow  = vt + NALL;
    float* Pcol  = Srow + NALL;                 // NBLK * NT floats (4.7 MB)
    float* Pcol2 = Pcol + (size_t)NBLK * NT;    // SPLIT * NT floats (fallback)
    float* outp  = (float*)d_out;

    (void)hipMemsetAsync(d_out, 0, (size_t)out_size * sizeof(float), stream);
    castA_kernel<<<NF, TPB, 0, stream>>>(A, Abf);

    // capture-safe, deterministic host-side queries
    int dev = 0, coop = 0, numCU = 0, occ = 0;
    (void)hipGetDevice(&dev);
    (void)hipDeviceGetAttribute(&coop, hipDeviceAttributeCooperativeLaunch, dev);
    (void)hipDeviceGetAttribute(&numCU, hipDeviceAttributeMultiprocessorCount, dev);
    (void)hipOccupancyMaxActiveBlocksPerMultiprocessor(&occ, (const void*)mega_kernel, TPB, 0);

    if (coop && (long)occ * numCU >= NBLK) {
        void* args[] = {
            (void*)&A, (void*)&tau_init, (void*)&GL_init,
            (void*)&GLbf, (void*)&mGh, (void*)&vGh, (void*)&Abf,
            (void*)&tauw, (void*)&mt, (void*)&vt,
            (void*)&Srow, (void*)&Pcol, (void*)&outp
        };
        (void)hipLaunchCooperativeKernel((void*)mega_kernel, dim3(NBLK), dim3(TPB),
                                         args, 0, stream);
    } else {
        const dim3 csGrid((NT + TPB - 1) / TPB, SPLIT);
        for (int it = 1; it <= ITERS; ++it) {
            const float bc1i = (float)(1.0 / (1.0 - pow(0.9,   (double)it)));
            const float bc2i = (float)(1.0 / (1.0 - pow(0.999, (double)it)));
            if (it == 1) {
                step_kernel<true><<<NBLK, TPB, 0, stream>>>(GL_init, GLbf, mGh, vGh, Abf,
                                                            tau_init, Srow, Pcol, bc1i, bc2i);
                colsum_kernel<<<csGrid, TPB, 0, stream>>>(Pcol, Pcol2);
                tau_kernel<true><<<NALL/TPB, TPB, 0, stream>>>(tau_init, tauw, mt, vt,
                                                               Srow, Pcol2, bc1i, bc2i);
            } else {
                step_kernel<false><<<NBLK, TPB, 0, stream>>>(nullptr, GLbf, mGh, vGh, Abf,
                                                             tauw, Srow, Pcol, bc1i, bc2i);
                colsum_kernel<<<csGrid, TPB, 0, stream>>>(Pcol, Pcol2);
                tau_kernel<false><<<NALL/TPB, TPB, 0, stream>>>(nullptr, tauw, mt, vt,
                                                                Srow, Pcol2, bc1i, bc2i);
            }
        }
        loss_kernel<<<NF, TPB, 0, stream>>>(GLbf, A, tauw, (float*)d_out);
    }
}

// Round 13
// 3708.593 us; speedup vs baseline: 3.9007x; 3.9007x over previous
//
#include <hip/hip_runtime.h>
#include <hip/hip_cooperative_groups.h>
#include <cmath>

namespace cg = cooperative_groups;

#define NALL 3072
#define NF   3056
#define NT   3056
#define NC4  764          // NT/4
#define RPB  4            // rows per block (764 blocks: ~3 blocks/CU, sync-safe)
#define NBLK (NF/RPB)     // 764 blocks
#define SPLIT 32          // column-sum reduction slices
#define RPS  ((NBLK + SPLIT - 1) / SPLIT)   // 24 rows per slice
#define CGRP ((NT + TPB - 1) / TPB)         // 12 column groups of 256
#define TPB  256
#define LRc  0.1f
#define AEPS 1e-8f
#define OEPS 0.1f
#define ITERS 100

__device__ __forceinline__ float sigf(float x) {
    return 1.0f / (1.0f + __expf(-x));
}

// ---- bf16 helpers: 4 elems <-> uint2 (8B), RTN-even rounding ----
__device__ __forceinline__ unsigned int pkbf(float x) {
    unsigned int t = __float_as_uint(x);
    return (t + 0x7FFFu + ((t >> 16) & 1u)) >> 16;
}
__device__ __forceinline__ float4 ld_bf4(const unsigned short* p) {
    uint2 u = *(const uint2*)p;
    float4 r;
    r.x = __uint_as_float(u.x << 16);
    r.y = __uint_as_float(u.x & 0xFFFF0000u);
    r.z = __uint_as_float(u.y << 16);
    r.w = __uint_as_float(u.y & 0xFFFF0000u);
    return r;
}
__device__ __forceinline__ void st_bf4(unsigned short* p, float4 v) {
    uint2 u;
    u.x = pkbf(v.x) | (pkbf(v.y) << 16);
    u.y = pkbf(v.z) | (pkbf(v.w) << 16);
    *(uint2*)p = u;
}

// ---------------- one-time cast of A[:NF, 16:] block to bf16 ----------------
__global__ void __launch_bounds__(TPB)
castA_kernel(const float* __restrict__ A, unsigned short* __restrict__ Abf)
{
    const int tid = threadIdx.x;
    const bool ok2 = tid < (NC4 - 512);
    const int i = blockIdx.x;
    const size_t abase = (size_t)i * NALL + 16;
    const size_t obase = (size_t)i * NT;
    #pragma unroll
    for (int k = 0; k < 3; ++k) {
        if (k == 2 && !ok2) continue;
        const int c4 = tid + 256*k;
        float4 a = *(const float4*)(A + abase + 4*c4);
        st_bf4(Abf + obase + 4*c4, a);
    }
}

// ======== shared step-phase body (device inline), used by both paths ========
template<bool FIRST>
__device__ __forceinline__ void step_rows(
    int b, const float* __restrict__ GL_init,
    unsigned short* __restrict__ GLbf, unsigned short* __restrict__ mG,
    unsigned short* __restrict__ vG, const unsigned short* __restrict__ Abf,
    const float* __restrict__ tau, float* __restrict__ Srow,
    float* __restrict__ Pcol, float bc1i, float bc2i,
    float* red /*shared[8]*/)
{
    const int tid  = threadIdx.x;
    const int lane = tid & 63;
    const int wv   = tid >> 6;
    const bool ok2 = tid < (NC4 - 512);
    const float c1 = 0.5f / (float)NF;
    const float c2 = 0.5f / ((float)NF * (float)NT);

    float4 tv[3];
    tv[0] = *(const float4*)(tau + 16 + 4 * tid);
    tv[1] = *(const float4*)(tau + 16 + 4 * (tid + 256));
    tv[2] = ok2 ? *(const float4*)(tau + 16 + 4 * (tid + 512)) : make_float4(0.f,0.f,0.f,0.f);

    float4 cacc[3];
    #pragma unroll
    for (int k = 0; k < 3; ++k) cacc[k] = make_float4(0.f,0.f,0.f,0.f);

    for (int rr = 0; rr < RPB; ++rr) {
        const int i = b * RPB + rr;
        const float tu = tau[i];
        const size_t g4base = (size_t)i * NC4;

        float4 gl[3], a4[3], m4[3], v4[3];
        #pragma unroll
        for (int k = 0; k < 3; ++k) {
            if (k == 2 && !ok2) continue;
            const int c4 = tid + 256*k;
            const size_t e = 4*(g4base + c4);
            gl[k] = FIRST ? ((const float4*)GL_init)[g4base + c4] : ld_bf4(GLbf + e);
            a4[k] = ld_bf4(Abf + e);
            if (FIRST) { m4[k] = make_float4(0.f,0.f,0.f,0.f); v4[k] = m4[k]; }
            else { m4[k] = ld_bf4(mG + e); v4[k] = ld_bf4(vG + e); }
        }

        float4 G4[3];
        float pl = 1.0f;
        #pragma unroll
        for (int k = 0; k < 3; ++k) {
            if (k == 2 && !ok2) continue;
            float4 g;
            g.x = sigf(gl[k].x); g.y = sigf(gl[k].y);
            g.z = sigf(gl[k].z); g.w = sigf(gl[k].w);
            G4[k] = g;
            pl *= fmaf(-2.0f*a4[k].x, g.x, 1.0f);
            pl *= fmaf(-2.0f*a4[k].y, g.y, 1.0f);
            pl *= fmaf(-2.0f*a4[k].z, g.z, 1.0f);
            pl *= fmaf(-2.0f*a4[k].w, g.w, 1.0f);
        }
        float pw = pl;
        #pragma unroll
        for (int off = 1; off < 64; off <<= 1) pw *= __shfl_xor(pw, off, 64);
        __syncthreads();
        if (lane == 0) red[wv] = pw;
        __syncthreads();
        const float p = red[0]*red[1]*red[2]*red[3];
        const float c1pp = c1 * (p + 1.0f);
        const bool pzero = (p == 0.0f);   // block-uniform

        float rowl = 0.0f;
        #pragma unroll
        for (int k = 0; k < 3; ++k) {
            if (k == 2 && !ok2) continue;
            const int c4 = tid + 256*k;
            const size_t e = 4*(g4base + c4);
            float4 glo, mo, vo;
            if (pzero) {
                #define COMPF(FLD) { \
                    const float g = G4[k].FLD; \
                    const float d = tu - tv[k].FLD + OEPS; \
                    const float r = fmaxf(d, 0.0f); \
                    const float gg = (c2 * (r*r)) * (g * (1.0f - g)); \
                    const float m2 = fmaf(0.9f, m4[k].FLD, 0.1f*gg); \
                    const float v2 = fmaf(0.999f, v4[k].FLD, 0.001f*gg*gg); \
                    const float den = __fsqrt_rn(v2 * bc2i) + AEPS; \
                    glo.FLD = gl[k].FLD - LRc * (m2 * bc1i) / den; \
                    mo.FLD = m2; vo.FLD = v2; \
                    const float w = g * r; \
                    rowl += w; cacc[k].FLD += w; }
                COMPF(x) COMPF(y) COMPF(z) COMPF(w)
                #undef COMPF
            } else {
                #define COMP(FLD) { \
                    const float g = G4[k].FLD; \
                    const float a = a4[k].FLD; \
                    const float f = fmaf(-2.0f*a, g, 1.0f); \
                    const float po = (f != 0.0f) ? __fdividef(p, f) : 0.0f; \
                    const float d = tu - tv[k].FLD + OEPS; \
                    const float r = fmaxf(d, 0.0f); \
                    const float gg = fmaf(c2, r*r, c1pp * po * (-2.0f*a)) * (g * (1.0f - g)); \
                    const float m2 = fmaf(0.9f, m4[k].FLD, 0.1f*gg); \
                    const float v2 = fmaf(0.999f, v4[k].FLD, 0.001f*gg*gg); \
                    const float den = __fsqrt_rn(v2 * bc2i) + AEPS; \
                    glo.FLD = gl[k].FLD - LRc * (m2 * bc1i) / den; \
                    mo.FLD = m2; vo.FLD = v2; \
                    const float w = g * r; \
                    rowl += w; cacc[k].FLD += w; }
                COMP(x) COMP(y) COMP(z) COMP(w)
                #undef COMP
            }
            st_bf4(GLbf + e, glo);
            st_bf4(mG + e, mo);
            st_bf4(vG + e, vo);
        }

        float sw = rowl;
        #pragma unroll
        for (int off = 1; off < 64; off <<= 1) sw += __shfl_xor(sw, off, 64);
        if (lane == 0) red[4+wv] = sw;
        __syncthreads();
        if (tid == 0) Srow[i] = (red[4]+red[5]) + (red[6]+red[7]);
    }

    float* pc = Pcol + (size_t)b * NT;
    #pragma unroll
    for (int k = 0; k < 3; ++k) {
        if (k == 2 && !ok2) continue;
        *(float4*)(pc + 4*(tid + 256*k)) = cacc[k];
    }
}

// ---------------- cooperative mega-kernel (3 grid.syncs/iter) ----------------
__global__ void __launch_bounds__(TPB, 4)
mega_kernel(const float* __restrict__ A, const float* __restrict__ tau_init,
            const float* __restrict__ GL_init,
            unsigned short* __restrict__ GLbf, unsigned short* __restrict__ mG,
            unsigned short* __restrict__ vG, const unsigned short* __restrict__ Abf,
            float* __restrict__ tauw, float* __restrict__ mt, float* __restrict__ vt,
            float* __restrict__ Srow, float* __restrict__ Pcol,
            float* __restrict__ Pcol2, float* __restrict__ out)
{
    cg::grid_group grid = cg::this_grid();
    __shared__ float red[8];
    __shared__ float redc[8];
    const int tid  = threadIdx.x;
    const int lane = tid & 63;
    const int wv   = tid >> 6;
    const bool ok2 = tid < (NC4 - 512);
    const int b    = blockIdx.x;
    const float ct = 1.0f / ((float)NF * (float)NT);

    double b1p = 1.0, b2p = 1.0;
    for (int it = 0; it < ITERS; ++it) {
        b1p *= 0.9; b2p *= 0.999;
        const float bc1i = (float)(1.0 / (1.0 - b1p));
        const float bc2i = (float)(1.0 / (1.0 - b2p));

        if (it == 0)
            step_rows<true >(b, GL_init, GLbf, mG, vG, Abf, tau_init, Srow, Pcol, bc1i, bc2i, red);
        else
            step_rows<false>(b, nullptr,  GLbf, mG, vG, Abf, tauw,     Srow, Pcol, bc1i, bc2i, red);

        grid.sync();

        // ---- phase A: coalesced partial column reduce (blocks 0..CGRP*SPLIT-1) ----
        if (b < CGRP * SPLIT) {
            const int cgp = b % CGRP;          // column group (0..11)
            const int s   = b / CGRP;          // slice (0..31)
            const int c   = cgp * TPB + tid;   // column
            if (c < NT) {
                const int r0 = s * RPS;
                const int r1 = (r0 + RPS < NBLK) ? (r0 + RPS) : NBLK;
                float a0=0.f,a1=0.f,a2=0.f,a3=0.f;
                const float* p = Pcol + (size_t)r0 * NT + c;
                int r = r0;
                for (; r + 4 <= r1; r += 4) {
                    a0 += p[0];
                    a1 += p[(size_t)NT];
                    a2 += p[(size_t)2*NT];
                    a3 += p[(size_t)3*NT];
                    p += (size_t)4*NT;
                }
                for (; r < r1; ++r) { a0 += *p; p += NT; }
                Pcol2[(size_t)s * NT + c] = (a0+a1)+(a2+a3);
            }
        }

        grid.sync();

        // ---- phase B: block b owns columns 4b..4b+3 -> tau[4b+16..4b+19] ----
        {
            // threads 0..127: t = s*4 + col; each loads one slice-partial
            float v = 0.0f;
            if (tid < 128) {
                const int s   = tid >> 2;
                const int col = tid & 3;
                v = Pcol2[(size_t)s * NT + 4*b + col];
            }
            // reduce over s within wave 0 (s=0..15) / wave 1 (s=16..31)
            #pragma unroll
            for (int off = 4; off < 64; off <<= 1) v += __shfl_xor(v, off, 64);
            __syncthreads();
            if (tid < 128 && lane < 4) redc[wv*4 + lane] = v;
            __syncthreads();
            if (tid < 4) {
                const float cs = redc[tid] + redc[4+tid];
                const int k = 4*b + 16 + tid;
                float g = (((k < NF) ? Srow[k] : 0.0f) - cs) * ct;
                const float t0 = (it == 0) ? tau_init[k] : tauw[k];
                const float m0 = (it == 0) ? 0.0f : mt[k];
                const float v0 = (it == 0) ? 0.0f : vt[k];
                const float m2 = fmaf(0.9f, m0, 0.1f*g);
                const float v2 = fmaf(0.999f, v0, 0.001f*g*g);
                const float den = __fsqrt_rn(v2 * bc2i) + AEPS;
                tauw[k] = t0 - LRc * (m2 * bc1i) / den;
                mt[k] = m2; vt[k] = v2;
            }
            if (b == 0 && tid >= 132 && tid < 148) {
                const int k = tid - 132;      // k = 0..15: row-sum term only
                float g = Srow[k] * ct;
                const float t0 = (it == 0) ? tau_init[k] : tauw[k];
                const float m0 = (it == 0) ? 0.0f : mt[k];
                const float v0 = (it == 0) ? 0.0f : vt[k];
                const float m2 = fmaf(0.9f, m0, 0.1f*g);
                const float v2 = fmaf(0.999f, v0, 0.001f*g*g);
                const float den = __fsqrt_rn(v2 * bc2i) + AEPS;
                tauw[k] = t0 - LRc * (m2 * bc1i) / den;
                mt[k] = m2; vt[k] = v2;
            }
        }
        grid.sync();
    }

    // ======== final loss (original fp32 A, bf16 final GL, final tauw) ========
    float lsum = 0.0f;
    for (int rr = 0; rr < RPB; ++rr) {
        const int i = b * RPB + rr;
        const float tu = tauw[i];
        const size_t g4base = (size_t)i * NC4;
        const size_t abase  = (size_t)i * NALL + 16;
        float pl = 1.0f, sl = 0.0f;
        #pragma unroll
        for (int k = 0; k < 3; ++k) {
            if (k == 2 && !ok2) continue;
            const int c4 = tid + 256*k;
            float4 gl = ld_bf4(GLbf + 4*(g4base + c4));
            float4 a  = *(const float4*)(A + abase + 4*c4);
            float4 tvv = *(const float4*)(tauw + 16 + 4*c4);
            #define LCOMP(FLD) { \
                const float g = sigf(gl.FLD); \
                pl *= fmaf(-2.0f*a.FLD, g, 1.0f); \
                const float r = fmaxf(tu - tvv.FLD + OEPS, 0.0f); \
                sl += g * r * r; }
            LCOMP(x) LCOMP(y) LCOMP(z) LCOMP(w)
            #undef LCOMP
        }
        float pw = pl, sw = sl;
        #pragma unroll
        for (int off = 1; off < 64; off <<= 1) {
            pw *= __shfl_xor(pw, off, 64);
            sw += __shfl_xor(sw, off, 64);
        }
        __syncthreads();
        if (lane == 0) { red[wv] = pw; red[4+wv] = sw; }
        __syncthreads();
        if (tid == 0) {
            const float p = red[0]*red[1]*red[2]*red[3];
            const float s = (red[4]+red[5]) + (red[6]+red[7]);
            lsum += 0.25f*(p+1.0f)*(p+1.0f)*(1.0f/(float)NF)
                  + 0.5f*s*(1.0f/((float)NF*(float)NT));
        }
    }
    if (tid == 0) atomicAdd(out, lsum);
}

// ================= fallback path (separate kernels, same math) =================
template<bool FIRST>
__global__ void __launch_bounds__(TPB)
step_kernel(const float* GLinit, unsigned short* __restrict__ GLbf,
            unsigned short* __restrict__ mG, unsigned short* __restrict__ vG,
            const unsigned short* __restrict__ Abf, const float* __restrict__ tau,
            float* __restrict__ Srow, float* __restrict__ Pcol,
            float bc1i, float bc2i)
{
    __shared__ float red[8];
    step_rows<FIRST>(blockIdx.x, GLinit, GLbf, mG, vG, Abf, tau, Srow, Pcol, bc1i, bc2i, red);
}

__global__ void __launch_bounds__(TPB)
colsum_kernel(const float* __restrict__ Pcol, float* __restrict__ Pcol2)
{
    const int c = blockIdx.x * TPB + threadIdx.x;
    if (c >= NT) return;
    const int s  = blockIdx.y;
    const int r0 = s * RPS;
    const int r1 = (r0 + RPS < NBLK) ? (r0 + RPS) : NBLK;
    float a[4];
    #pragma unroll
    for (int u = 0; u < 4; ++u) a[u] = 0.0f;
    const float* p = Pcol + (size_t)r0 * NT + c;
    int r = r0;
    for (; r + 4 <= r1; r += 4) {
        #pragma unroll
        for (int u = 0; u < 4; ++u) a[u] += p[(size_t)u * NT];
        p += (size_t)4 * NT;
    }
    for (; r < r1; ++r) { a[0] += *p; p += NT; }
    Pcol2[(size_t)s * NT + c] = (a[0]+a[1])+(a[2]+a[3]);
}

template<bool FIRST>
__global__ void __launch_bounds__(TPB)
tau_kernel(const float* tinit, float* tauw,
           float* __restrict__ mt, float* __restrict__ vt,
           const float* __restrict__ Srow, const float* __restrict__ Pcol2,
           float bc1i, float bc2i)
{
    const int k = blockIdx.x * TPB + threadIdx.x;
    if (k >= NALL) return;
    const float ct = 1.0f / ((float)NF * (float)NT);
    float g = 0.0f;
    if (k < NF) g = Srow[k];
    if (k >= 16) {
        const int j = k - 16;
        float s = 0.0f;
        #pragma unroll
        for (int t = 0; t < SPLIT; ++t) s += Pcol2[(size_t)t * NT + j];
        g -= s;
    }
    g *= ct;
    const float t0 = FIRST ? tinit[k] : tauw[k];
    const float m0 = FIRST ? 0.0f : mt[k];
    const float v0 = FIRST ? 0.0f : vt[k];
    const float m2 = fmaf(0.9f, m0, 0.1f*g);
    const float v2 = fmaf(0.999f, v0, 0.001f*g*g);
    const float den = __fsqrt_rn(v2 * bc2i) + AEPS;
    tauw[k] = t0 - LRc * (m2 * bc1i) / den;
    mt[k] = m2; vt[k] = v2;
}

__global__ void __launch_bounds__(TPB)
loss_kernel(const unsigned short* __restrict__ GLbf, const float* __restrict__ A,
            const float* __restrict__ tau, float* __restrict__ out)
{
    __shared__ float red[8];
    const int tid = threadIdx.x;
    const int lane = tid & 63, wv = tid >> 6;
    const bool ok2 = tid < (NC4 - 512);
    const int i = blockIdx.x;
    const float tu = tau[i];
    const size_t g4base = (size_t)i * NC4;
    const size_t abase  = (size_t)i * NALL + 16;
    float pl = 1.0f, sl = 0.0f;
    #pragma unroll
    for (int k = 0; k < 3; ++k) {
        if (k == 2 && !ok2) continue;
        const int c4 = tid + 256*k;
        float4 gl = ld_bf4(GLbf + 4*(g4base + c4));
        float4 a  = *(const float4*)(A + abase + 4*c4);
        float4 tv = *(const float4*)(tau + 16 + 4*c4);
        #define LCOMP(FLD) { \
            const float g = sigf(gl.FLD); \
            pl *= fmaf(-2.0f*a.FLD, g, 1.0f); \
            const float r = fmaxf(tu - tv.FLD + OEPS, 0.0f); \
            sl += g * r * r; }
        LCOMP(x) LCOMP(y) LCOMP(z) LCOMP(w)
        #undef LCOMP
    }
    float pw = pl, sw = sl;
    #pragma unroll
    for (int off = 1; off < 64; off <<= 1) {
        pw *= __shfl_xor(pw, off, 64);
        sw += __shfl_xor(sw, off, 64);
    }
    if (lane == 0) { red[wv] = pw; red[4+wv] = sw; }
    __syncthreads();
    if (tid == 0) {
        const float p = red[0]*red[1]*red[2]*red[3];
        const float s = (red[4]+red[5]) + (red[6]+red[7]);
        const float v = 0.25f*(p+1.0f)*(p+1.0f)*(1.0f/(float)NF)
                      + 0.5f*s*(1.0f/((float)NF*(float)NT));
        atomicAdd(out, v);
    }
}

// ---------------- host ----------------
extern "C" void kernel_launch(void* const* d_in, const int* in_sizes, int n_in,
                              void* d_out, int out_size, void* d_ws, size_t ws_size,
                              hipStream_t stream)
{
    const float* A        = (const float*)d_in[0];
    const float* tau_init = (const float*)d_in[1];
    const float* GL_init  = (const float*)d_in[2];

    const size_t mat = (size_t)NF * NT;
    unsigned short* GLbf = (unsigned short*)d_ws;         // mat bf16
    unsigned short* mGh  = GLbf + mat;                    // mat bf16
    unsigned short* vGh  = mGh + mat;                     // mat bf16
    unsigned short* Abf  = vGh + mat;                     // mat bf16
    float* tauw  = (float*)(Abf + mat);
    float* mt    = tauw + NALL;
    float* vt    = mt + NALL;
    float* Srow  = vt + NALL;
    float* Pcol  = Srow + NALL;                 // NBLK * NT floats (9.3 MB)
    float* Pcol2 = Pcol + (size_t)NBLK * NT;    // SPLIT * NT floats
    float* outp  = (float*)d_out;

    (void)hipMemsetAsync(d_out, 0, (size_t)out_size * sizeof(float), stream);
    castA_kernel<<<NF, TPB, 0, stream>>>(A, Abf);

    // capture-safe, deterministic host-side queries
    int dev = 0, coop = 0, numCU = 0, occ = 0;
    (void)hipGetDevice(&dev);
    (void)hipDeviceGetAttribute(&coop, hipDeviceAttributeCooperativeLaunch, dev);
    (void)hipDeviceGetAttribute(&numCU, hipDeviceAttributeMultiprocessorCount, dev);
    (void)hipOccupancyMaxActiveBlocksPerMultiprocessor(&occ, (const void*)mega_kernel, TPB, 0);

    if (coop && (long)occ * numCU >= NBLK) {
        void* args[] = {
            (void*)&A, (void*)&tau_init, (void*)&GL_init,
            (void*)&GLbf, (void*)&mGh, (void*)&vGh, (void*)&Abf,
            (void*)&tauw, (void*)&mt, (void*)&vt,
            (void*)&Srow, (void*)&Pcol, (void*)&Pcol2, (void*)&outp
        };
        (void)hipLaunchCooperativeKernel((void*)mega_kernel, dim3(NBLK), dim3(TPB),
                                         args, 0, stream);
    } else {
        const dim3 csGrid(CGRP, SPLIT);
        for (int it = 1; it <= ITERS; ++it) {
            const float bc1i = (float)(1.0 / (1.0 - pow(0.9,   (double)it)));
            const float bc2i = (float)(1.0 / (1.0 - pow(0.999, (double)it)));
            if (it == 1) {
                step_kernel<true><<<NBLK, TPB, 0, stream>>>(GL_init, GLbf, mGh, vGh, Abf,
                                                            tau_init, Srow, Pcol, bc1i, bc2i);
                colsum_kernel<<<csGrid, TPB, 0, stream>>>(Pcol, Pcol2);
                tau_kernel<true><<<NALL/TPB, TPB, 0, stream>>>(tau_init, tauw, mt, vt,
                                                               Srow, Pcol2, bc1i, bc2i);
            } else {
                step_kernel<false><<<NBLK, TPB, 0, stream>>>(nullptr, GLbf, mGh, vGh, Abf,
                                                             tauw, Srow, Pcol, bc1i, bc2i);
                colsum_kernel<<<csGrid, TPB, 0, stream>>>(Pcol, Pcol2);
                tau_kernel<false><<<NALL/TPB, TPB, 0, stream>>>(nullptr, tauw, mt, vt,
                                                                Srow, Pcol2, bc1i, bc2i);
            }
        }
        loss_kernel<<<NF, TPB, 0, stream>>>(GLbf, A, tauw, (float*)d_out);
    }
}

// Round 14
// 3687.220 us; speedup vs baseline: 3.9234x; 1.0058x over previous
//
#include <hip/hip_runtime.h>
#include <hip/hip_cooperative_groups.h>
#include <cmath>

namespace cg = cooperative_groups;

#define NALL 3072
#define NF   3056
#define NT   3056
#define NC4  764          // NT/4
#define RPB  4            // rows per block (764 blocks: ~3 blocks/CU)
#define NBLK (NF/RPB)     // 764 blocks
#define NQ   (NALL/4)     // 768 tau quads
#define CB   (NT/16)      // 191 phase-2 reducer blocks
#define SPLIT 32          // fallback colsum slices
#define RPS  ((NBLK + SPLIT - 1) / SPLIT)
#define TPB  256
#define CGRP ((NT + TPB - 1) / TPB)
#define LRc  0.1f
#define AEPS 1e-8f
#define OEPS 0.1f
#define ITERS 100

__device__ __forceinline__ float sigf(float x) {
    return 1.0f / (1.0f + __expf(-x));
}

// ---- bf16 helpers: 4 elems <-> uint2 (8B), RTN-even rounding ----
__device__ __forceinline__ unsigned int pkbf(float x) {
    unsigned int t = __float_as_uint(x);
    return (t + 0x7FFFu + ((t >> 16) & 1u)) >> 16;
}
__device__ __forceinline__ float4 ld_bf4(const unsigned short* p) {
    uint2 u = *(const uint2*)p;
    float4 r;
    r.x = __uint_as_float(u.x << 16);
    r.y = __uint_as_float(u.x & 0xFFFF0000u);
    r.z = __uint_as_float(u.y << 16);
    r.w = __uint_as_float(u.y & 0xFFFF0000u);
    return r;
}
__device__ __forceinline__ void st_bf4(unsigned short* p, float4 v) {
    uint2 u;
    u.x = pkbf(v.x) | (pkbf(v.y) << 16);
    u.y = pkbf(v.z) | (pkbf(v.w) << 16);
    *(uint2*)p = u;
}

// ---------------- one-time cast of A[:NF, 16:] block to bf16 ----------------
__global__ void __launch_bounds__(TPB)
castA_kernel(const float* __restrict__ A, unsigned short* __restrict__ Abf)
{
    const int tid = threadIdx.x;
    const bool ok2 = tid < (NC4 - 512);
    const int i = blockIdx.x;
    const size_t abase = (size_t)i * NALL + 16;
    const size_t obase = (size_t)i * NT;
    #pragma unroll
    for (int k = 0; k < 3; ++k) {
        if (k == 2 && !ok2) continue;
        const int c4 = tid + 256*k;
        float4 a = *(const float4*)(A + abase + 4*c4);
        st_bf4(Abf + obase + 4*c4, a);
    }
}

// ---------------- cooperative mega-kernel: 2 grid.syncs per iteration ----------------
__global__ void __launch_bounds__(TPB, 4)
mega_kernel(const float* __restrict__ A, const float* __restrict__ tau_init,
            const float* __restrict__ GL_init,
            unsigned short* __restrict__ GLbf, unsigned short* __restrict__ mG,
            unsigned short* __restrict__ vG, const unsigned short* __restrict__ Abf,
            float* __restrict__ tau_g,  /* [2][NALL] */
            float* __restrict__ mt_g,   /* [2][NALL] */
            float* __restrict__ vt_g,   /* [2][NALL] */
            float* __restrict__ Srow_g, /* [2][NALL] */
            float* __restrict__ Pcol,   /* [NBLK][NT] */
            float* __restrict__ Gcol,   /* [NT] */
            float* __restrict__ out)
{
    cg::grid_group grid = cg::this_grid();
    __shared__ float tau_s[NALL];   // 12 KB: per-block tau copy
    __shared__ float red[8];
    __shared__ float redc[64];
    const int tid  = threadIdx.x;
    const int lane = tid & 63;
    const int wv   = tid >> 6;
    const bool ok2 = tid < (NC4 - 512);
    const int b    = blockIdx.x;
    const float c1 = 0.5f / (float)NF;
    const float c2 = 0.5f / ((float)NF * (float)NT);
    const float ct = 1.0f / ((float)NF * (float)NT);

    double b1p = 1.0, b2p = 1.0;   // 0.9^it, 0.999^it at loop top
    for (int it = 0; it < ITERS; ++it) {
        const float bc1t = (it > 0) ? (float)(1.0/(1.0 - b1p)) : 0.f;  // tau: t = it
        const float bc2t = (it > 0) ? (float)(1.0/(1.0 - b2p)) : 0.f;
        b1p *= 0.9; b2p *= 0.999;
        const float bc1i = (float)(1.0/(1.0 - b1p));   // GL: t = it+1
        const float bc2i = (float)(1.0/(1.0 - b2p));
        const int rp = (it - 1) & 1, wp = it & 1;

        // ======== phase 1a: tau Adam update (redundant per block) into LDS ========
        #pragma unroll
        for (int j = 0; j < 3; ++j) {
            const int q = tid + 256*j;   // quad index 0..767
            float4 tnew, m2q = make_float4(0.f,0.f,0.f,0.f), v2q = m2q;
            if (it == 0) {
                tnew = ((const float4*)tau_init)[q];
            } else {
                const float4 t0 = ((const float4*)(tau_g + rp*NALL))[q];
                float4 sr = make_float4(0.f,0.f,0.f,0.f), gc = sr, m0 = sr, v0 = sr;
                if (q < NF/4) sr = ((const float4*)(Srow_g + rp*NALL))[q];
                if (q >= 4)   gc = ((const float4*)Gcol)[q - 4];
                if (it > 1) { m0 = ((const float4*)(mt_g + rp*NALL))[q];
                              v0 = ((const float4*)(vt_g + rp*NALL))[q]; }
                #define TADAM(F) { \
                    const float g = (sr.F - gc.F) * ct; \
                    const float m2 = fmaf(0.9f, m0.F, 0.1f*g); \
                    const float v2 = fmaf(0.999f, v0.F, 0.001f*g*g); \
                    const float den = __fsqrt_rn(v2 * bc2t) + AEPS; \
                    tnew.F = t0.F - LRc * (m2 * bc1t) / den; \
                    m2q.F = m2; v2q.F = v2; }
                TADAM(x) TADAM(y) TADAM(z) TADAM(w)
                #undef TADAM
            }
            ((float4*)tau_s)[q] = tnew;
            if (b == tid) {   // designated writer: block b<256, thread tid==b, quads {b, b+256, b+512}
                ((float4*)(tau_g + wp*NALL))[q] = tnew;
                if (it > 0) {
                    ((float4*)(mt_g + wp*NALL))[q] = m2q;
                    ((float4*)(vt_g + wp*NALL))[q] = v2q;
                }
            }
        }
        __syncthreads();

        // ======== phase 1b: step (tau from LDS) ========
        float4 tv[3];
        tv[0] = ((const float4*)tau_s)[4 + tid];
        tv[1] = ((const float4*)tau_s)[4 + tid + 256];
        tv[2] = ok2 ? ((const float4*)tau_s)[4 + tid + 512] : make_float4(0.f,0.f,0.f,0.f);

        float4 cacc[3];
        #pragma unroll
        for (int k = 0; k < 3; ++k) cacc[k] = make_float4(0.f,0.f,0.f,0.f);

        const bool first = (it == 0);
        for (int rr = 0; rr < RPB; ++rr) {
            const int i = b * RPB + rr;
            const float tu = tau_s[i];
            const size_t g4base = (size_t)i * NC4;

            float4 gl[3], a4[3], m4[3], v4[3];
            #pragma unroll
            for (int k = 0; k < 3; ++k) {
                if (k == 2 && !ok2) continue;
                const int c4 = tid + 256*k;
                const size_t e = 4*(g4base + c4);
                gl[k] = first ? ((const float4*)GL_init)[g4base + c4] : ld_bf4(GLbf + e);
                a4[k] = ld_bf4(Abf + e);
                if (first) { m4[k] = make_float4(0.f,0.f,0.f,0.f); v4[k] = m4[k]; }
                else { m4[k] = ld_bf4(mG + e); v4[k] = ld_bf4(vG + e); }
            }

            float4 G4[3];
            float pl = 1.0f;
            #pragma unroll
            for (int k = 0; k < 3; ++k) {
                if (k == 2 && !ok2) continue;
                float4 g;
                g.x = sigf(gl[k].x); g.y = sigf(gl[k].y);
                g.z = sigf(gl[k].z); g.w = sigf(gl[k].w);
                G4[k] = g;
                pl *= fmaf(-2.0f*a4[k].x, g.x, 1.0f);
                pl *= fmaf(-2.0f*a4[k].y, g.y, 1.0f);
                pl *= fmaf(-2.0f*a4[k].z, g.z, 1.0f);
                pl *= fmaf(-2.0f*a4[k].w, g.w, 1.0f);
            }
            float pw = pl;
            #pragma unroll
            for (int off = 1; off < 64; off <<= 1) pw *= __shfl_xor(pw, off, 64);
            __syncthreads();
            if (lane == 0) red[wv] = pw;
            __syncthreads();
            const float p = red[0]*red[1]*red[2]*red[3];
            const float c1pp = c1 * (p + 1.0f);
            const bool pzero = (p == 0.0f);

            float rowl = 0.0f;
            #pragma unroll
            for (int k = 0; k < 3; ++k) {
                if (k == 2 && !ok2) continue;
                const int c4 = tid + 256*k;
                const size_t e = 4*(g4base + c4);
                float4 glo, mo, vo;
                if (pzero) {
                    #define COMPF(FLD) { \
                        const float g = G4[k].FLD; \
                        const float d = tu - tv[k].FLD + OEPS; \
                        const float r = fmaxf(d, 0.0f); \
                        const float gg = (c2 * (r*r)) * (g * (1.0f - g)); \
                        const float m2 = fmaf(0.9f, m4[k].FLD, 0.1f*gg); \
                        const float v2 = fmaf(0.999f, v4[k].FLD, 0.001f*gg*gg); \
                        const float den = __fsqrt_rn(v2 * bc2i) + AEPS; \
                        glo.FLD = gl[k].FLD - LRc * (m2 * bc1i) / den; \
                        mo.FLD = m2; vo.FLD = v2; \
                        const float w = g * r; \
                        rowl += w; cacc[k].FLD += w; }
                    COMPF(x) COMPF(y) COMPF(z) COMPF(w)
                    #undef COMPF
                } else {
                    #define COMP(FLD) { \
                        const float g = G4[k].FLD; \
                        const float a = a4[k].FLD; \
                        const float f = fmaf(-2.0f*a, g, 1.0f); \
                        const float po = (f != 0.0f) ? __fdividef(p, f) : 0.0f; \
                        const float d = tu - tv[k].FLD + OEPS; \
                        const float r = fmaxf(d, 0.0f); \
                        const float gg = fmaf(c2, r*r, c1pp * po * (-2.0f*a)) * (g * (1.0f - g)); \
                        const float m2 = fmaf(0.9f, m4[k].FLD, 0.1f*gg); \
                        const float v2 = fmaf(0.999f, v4[k].FLD, 0.001f*gg*gg); \
                        const float den = __fsqrt_rn(v2 * bc2i) + AEPS; \
                        glo.FLD = gl[k].FLD - LRc * (m2 * bc1i) / den; \
                        mo.FLD = m2; vo.FLD = v2; \
                        const float w = g * r; \
                        rowl += w; cacc[k].FLD += w; }
                    COMP(x) COMP(y) COMP(z) COMP(w)
                    #undef COMP
                }
                st_bf4(GLbf + e, glo);
                st_bf4(mG + e, mo);
                st_bf4(vG + e, vo);
            }

            float sw = rowl;
            #pragma unroll
            for (int off = 1; off < 64; off <<= 1) sw += __shfl_xor(sw, off, 64);
            if (lane == 0) red[4+wv] = sw;
            __syncthreads();
            if (tid == 0) (Srow_g + wp*NALL)[i] = (red[4]+red[5]) + (red[6]+red[7]);
        }

        {
            float* pc = Pcol + (size_t)b * NT;
            #pragma unroll
            for (int k = 0; k < 3; ++k) {
                if (k == 2 && !ok2) continue;
                *(float4*)(pc + 4*(tid + 256*k)) = cacc[k];
            }
        }

        grid.sync();

        // ======== phase 2: coalesced column reduce (191 blocks, 16 cols each) ========
        if (b < CB) {
            const int col = 16*b + (tid & 15);
            float acc4[4] = {0.f,0.f,0.f,0.f};
            for (int rb = 0; rb < NBLK; rb += 64) {
                #pragma unroll
                for (int u = 0; u < 4; ++u) {
                    const int r = rb + 16*u + (tid >> 4);
                    if (r < NBLK) acc4[u] += Pcol[(size_t)r*NT + col];
                }
            }
            float acc = (acc4[0]+acc4[1]) + (acc4[2]+acc4[3]);
            acc += __shfl_xor(acc, 16, 64);
            acc += __shfl_xor(acc, 32, 64);
            if (lane < 16) redc[wv*16 + lane] = acc;
        }
        __syncthreads();
        if (b < CB && tid < 16) {
            Gcol[16*b + tid] = (redc[tid] + redc[16+tid]) + (redc[32+tid] + redc[48+tid]);
        }
        grid.sync();
    }

    // ======== final tau update (t = ITERS) into LDS ========
    {
        const float bc1t = (float)(1.0/(1.0 - b1p));
        const float bc2t = (float)(1.0/(1.0 - b2p));
        const int rp = (ITERS - 1) & 1;
        #pragma unroll
        for (int j = 0; j < 3; ++j) {
            const int q = tid + 256*j;
            const float4 t0 = ((const float4*)(tau_g + rp*NALL))[q];
            float4 sr = make_float4(0.f,0.f,0.f,0.f), gc = sr;
            if (q < NF/4) sr = ((const float4*)(Srow_g + rp*NALL))[q];
            if (q >= 4)   gc = ((const float4*)Gcol)[q - 4];
            const float4 m0 = ((const float4*)(mt_g + rp*NALL))[q];
            const float4 v0 = ((const float4*)(vt_g + rp*NALL))[q];
            float4 tnew;
            #define TADAM(F) { \
                const float g = (sr.F - gc.F) * ct; \
                const float m2 = fmaf(0.9f, m0.F, 0.1f*g); \
                const float v2 = fmaf(0.999f, v0.F, 0.001f*g*g); \
                const float den = __fsqrt_rn(v2 * bc2t) + AEPS; \
                tnew.F = t0.F - LRc * (m2 * bc1t) / den; }
            TADAM(x) TADAM(y) TADAM(z) TADAM(w)
            #undef TADAM
            ((float4*)tau_s)[q] = tnew;
        }
    }
    __syncthreads();

    // ======== final loss (original fp32 A, bf16 final GL, final tau in LDS) ========
    float lsum = 0.0f;
    for (int rr = 0; rr < RPB; ++rr) {
        const int i = b * RPB + rr;
        const float tu = tau_s[i];
        const size_t g4base = (size_t)i * NC4;
        const size_t abase  = (size_t)i * NALL + 16;
        float pl = 1.0f, sl = 0.0f;
        #pragma unroll
        for (int k = 0; k < 3; ++k) {
            if (k == 2 && !ok2) continue;
            const int c4 = tid + 256*k;
            float4 gl = ld_bf4(GLbf + 4*(g4base + c4));
            float4 a  = *(const float4*)(A + abase + 4*c4);
            float4 tvv = ((const float4*)tau_s)[4 + c4];
            #define LCOMP(FLD) { \
                const float g = sigf(gl.FLD); \
                pl *= fmaf(-2.0f*a.FLD, g, 1.0f); \
                const float r = fmaxf(tu - tvv.FLD + OEPS, 0.0f); \
                sl += g * r * r; }
            LCOMP(x) LCOMP(y) LCOMP(z) LCOMP(w)
            #undef LCOMP
        }
        float pw = pl, sw = sl;
        #pragma unroll
        for (int off = 1; off < 64; off <<= 1) {
            pw *= __shfl_xor(pw, off, 64);
            sw += __shfl_xor(sw, off, 64);
        }
        __syncthreads();
        if (lane == 0) { red[wv] = pw; red[4+wv] = sw; }
        __syncthreads();
        if (tid == 0) {
            const float p = red[0]*red[1]*red[2]*red[3];
            const float s = (red[4]+red[5]) + (red[6]+red[7]);
            lsum += 0.25f*(p+1.0f)*(p+1.0f)*(1.0f/(float)NF)
                  + 0.5f*s*(1.0f/((float)NF*(float)NT));
        }
    }
    if (tid == 0) atomicAdd(out, lsum);
}

// ================= fallback path (round-13 structure, known-good) =================
template<bool FIRST>
__device__ __forceinline__ void step_rows_fb(
    int b, const float* __restrict__ GL_init,
    unsigned short* __restrict__ GLbf, unsigned short* __restrict__ mG,
    unsigned short* __restrict__ vG, const unsigned short* __restrict__ Abf,
    const float* __restrict__ tau, float* __restrict__ Srow,
    float* __restrict__ Pcol, float bc1i, float bc2i, float* red)
{
    const int tid  = threadIdx.x;
    const int lane = tid & 63;
    const int wv   = tid >> 6;
    const bool ok2 = tid < (NC4 - 512);
    const float c1 = 0.5f / (float)NF;
    const float c2 = 0.5f / ((float)NF * (float)NT);

    float4 tv[3];
    tv[0] = *(const float4*)(tau + 16 + 4 * tid);
    tv[1] = *(const float4*)(tau + 16 + 4 * (tid + 256));
    tv[2] = ok2 ? *(const float4*)(tau + 16 + 4 * (tid + 512)) : make_float4(0.f,0.f,0.f,0.f);

    float4 cacc[3];
    #pragma unroll
    for (int k = 0; k < 3; ++k) cacc[k] = make_float4(0.f,0.f,0.f,0.f);

    for (int rr = 0; rr < RPB; ++rr) {
        const int i = b * RPB + rr;
        const float tu = tau[i];
        const size_t g4base = (size_t)i * NC4;

        float4 gl[3], a4[3], m4[3], v4[3];
        #pragma unroll
        for (int k = 0; k < 3; ++k) {
            if (k == 2 && !ok2) continue;
            const int c4 = tid + 256*k;
            const size_t e = 4*(g4base + c4);
            gl[k] = FIRST ? ((const float4*)GL_init)[g4base + c4] : ld_bf4(GLbf + e);
            a4[k] = ld_bf4(Abf + e);
            if (FIRST) { m4[k] = make_float4(0.f,0.f,0.f,0.f); v4[k] = m4[k]; }
            else { m4[k] = ld_bf4(mG + e); v4[k] = ld_bf4(vG + e); }
        }

        float4 G4[3];
        float pl = 1.0f;
        #pragma unroll
        for (int k = 0; k < 3; ++k) {
            if (k == 2 && !ok2) continue;
            float4 g;
            g.x = sigf(gl[k].x); g.y = sigf(gl[k].y);
            g.z = sigf(gl[k].z); g.w = sigf(gl[k].w);
            G4[k] = g;
            pl *= fmaf(-2.0f*a4[k].x, g.x, 1.0f);
            pl *= fmaf(-2.0f*a4[k].y, g.y, 1.0f);
            pl *= fmaf(-2.0f*a4[k].z, g.z, 1.0f);
            pl *= fmaf(-2.0f*a4[k].w, g.w, 1.0f);
        }
        float pw = pl;
        #pragma unroll
        for (int off = 1; off < 64; off <<= 1) pw *= __shfl_xor(pw, off, 64);
        __syncthreads();
        if (lane == 0) red[wv] = pw;
        __syncthreads();
        const float p = red[0]*red[1]*red[2]*red[3];
        const float c1pp = c1 * (p + 1.0f);
        const bool pzero = (p == 0.0f);

        float rowl = 0.0f;
        #pragma unroll
        for (int k = 0; k < 3; ++k) {
            if (k == 2 && !ok2) continue;
            const int c4 = tid + 256*k;
            const size_t e = 4*(g4base + c4);
            float4 glo, mo, vo;
            if (pzero) {
                #define COMPF(FLD) { \
                    const float g = G4[k].FLD; \
                    const float d = tu - tv[k].FLD + OEPS; \
                    const float r = fmaxf(d, 0.0f); \
                    const float gg = (c2 * (r*r)) * (g * (1.0f - g)); \
                    const float m2 = fmaf(0.9f, m4[k].FLD, 0.1f*gg); \
                    const float v2 = fmaf(0.999f, v4[k].FLD, 0.001f*gg*gg); \
                    const float den = __fsqrt_rn(v2 * bc2i) + AEPS; \
                    glo.FLD = gl[k].FLD - LRc * (m2 * bc1i) / den; \
                    mo.FLD = m2; vo.FLD = v2; \
                    const float w = g * r; \
                    rowl += w; cacc[k].FLD += w; }
                COMPF(x) COMPF(y) COMPF(z) COMPF(w)
                #undef COMPF
            } else {
                #define COMP(FLD) { \
                    const float g = G4[k].FLD; \
                    const float a = a4[k].FLD; \
                    const float f = fmaf(-2.0f*a, g, 1.0f); \
                    const float po = (f != 0.0f) ? __fdividef(p, f) : 0.0f; \
                    const float d = tu - tv[k].FLD + OEPS; \
                    const float r = fmaxf(d, 0.0f); \
                    const float gg = fmaf(c2, r*r, c1pp * po * (-2.0f*a)) * (g * (1.0f - g)); \
                    const float m2 = fmaf(0.9f, m4[k].FLD, 0.1f*gg); \
                    const float v2 = fmaf(0.999f, v4[k].FLD, 0.001f*gg*gg); \
                    const float den = __fsqrt_rn(v2 * bc2i) + AEPS; \
                    glo.FLD = gl[k].FLD - LRc * (m2 * bc1i) / den; \
                    mo.FLD = m2; vo.FLD = v2; \
                    const float w = g * r; \
                    rowl += w; cacc[k].FLD += w; }
                COMP(x) COMP(y) COMP(z) COMP(w)
                #undef COMP
            }
            st_bf4(GLbf + e, glo);
            st_bf4(mG + e, mo);
            st_bf4(vG + e, vo);
        }

        float sw = rowl;
        #pragma unroll
        for (int off = 1; off < 64; off <<= 1) sw += __shfl_xor(sw, off, 64);
        if (lane == 0) red[4+wv] = sw;
        __syncthreads();
        if (tid == 0) Srow[i] = (red[4]+red[5]) + (red[6]+red[7]);
    }

    float* pc = Pcol + (size_t)b * NT;
    #pragma unroll
    for (int k = 0; k < 3; ++k) {
        if (k == 2 && !ok2) continue;
        *(float4*)(pc + 4*(tid + 256*k)) = cacc[k];
    }
}

template<bool FIRST>
__global__ void __launch_bounds__(TPB)
step_kernel(const float* GLinit, unsigned short* __restrict__ GLbf,
            unsigned short* __restrict__ mG, unsigned short* __restrict__ vG,
            const unsigned short* __restrict__ Abf, const float* __restrict__ tau,
            float* __restrict__ Srow, float* __restrict__ Pcol,
            float bc1i, float bc2i)
{
    __shared__ float red[8];
    step_rows_fb<FIRST>(blockIdx.x, GLinit, GLbf, mG, vG, Abf, tau, Srow, Pcol, bc1i, bc2i, red);
}

__global__ void __launch_bounds__(TPB)
colsum_kernel(const float* __restrict__ Pcol, float* __restrict__ Pcol2)
{
    const int c = blockIdx.x * TPB + threadIdx.x;
    if (c >= NT) return;
    const int s  = blockIdx.y;
    const int r0 = s * RPS;
    const int r1 = (r0 + RPS < NBLK) ? (r0 + RPS) : NBLK;
    float a[4] = {0.f,0.f,0.f,0.f};
    const float* p = Pcol + (size_t)r0 * NT + c;
    int r = r0;
    for (; r + 4 <= r1; r += 4) {
        #pragma unroll
        for (int u = 0; u < 4; ++u) a[u] += p[(size_t)u * NT];
        p += (size_t)4 * NT;
    }
    for (; r < r1; ++r) { a[0] += *p; p += NT; }
    Pcol2[(size_t)s * NT + c] = (a[0]+a[1])+(a[2]+a[3]);
}

template<bool FIRST>
__global__ void __launch_bounds__(TPB)
tau_kernel(const float* tinit, float* tauw,
           float* __restrict__ mt, float* __restrict__ vt,
           const float* __restrict__ Srow, const float* __restrict__ Pcol2,
           float bc1i, float bc2i)
{
    const int k = blockIdx.x * TPB + threadIdx.x;
    if (k >= NALL) return;
    const float ct = 1.0f / ((float)NF * (float)NT);
    float g = 0.0f;
    if (k < NF) g = Srow[k];
    if (k >= 16) {
        const int j = k - 16;
        float s = 0.0f;
        #pragma unroll
        for (int t = 0; t < SPLIT; ++t) s += Pcol2[(size_t)t * NT + j];
        g -= s;
    }
    g *= ct;
    const float t0 = FIRST ? tinit[k] : tauw[k];
    const float m0 = FIRST ? 0.0f : mt[k];
    const float v0 = FIRST ? 0.0f : vt[k];
    const float m2 = fmaf(0.9f, m0, 0.1f*g);
    const float v2 = fmaf(0.999f, v0, 0.001f*g*g);
    const float den = __fsqrt_rn(v2 * bc2i) + AEPS;
    tauw[k] = t0 - LRc * (m2 * bc1i) / den;
    mt[k] = m2; vt[k] = v2;
}

__global__ void __launch_bounds__(TPB)
loss_kernel(const unsigned short* __restrict__ GLbf, const float* __restrict__ A,
            const float* __restrict__ tau, float* __restrict__ out)
{
    __shared__ float red[8];
    const int tid = threadIdx.x;
    const int lane = tid & 63, wv = tid >> 6;
    const bool ok2 = tid < (NC4 - 512);
    const int i = blockIdx.x;
    const float tu = tau[i];
    const size_t g4base = (size_t)i * NC4;
    const size_t abase  = (size_t)i * NALL + 16;
    float pl = 1.0f, sl = 0.0f;
    #pragma unroll
    for (int k = 0; k < 3; ++k) {
        if (k == 2 && !ok2) continue;
        const int c4 = tid + 256*k;
        float4 gl = ld_bf4(GLbf + 4*(g4base + c4));
        float4 a  = *(const float4*)(A + abase + 4*c4);
        float4 tv = *(const float4*)(tau + 16 + 4*c4);
        #define LCOMP(FLD) { \
            const float g = sigf(gl.FLD); \
            pl *= fmaf(-2.0f*a.FLD, g, 1.0f); \
            const float r = fmaxf(tu - tv.FLD + OEPS, 0.0f); \
            sl += g * r * r; }
        LCOMP(x) LCOMP(y) LCOMP(z) LCOMP(w)
        #undef LCOMP
    }
    float pw = pl, sw = sl;
    #pragma unroll
    for (int off = 1; off < 64; off <<= 1) {
        pw *= __shfl_xor(pw, off, 64);
        sw += __shfl_xor(sw, off, 64);
    }
    if (lane == 0) { red[wv] = pw; red[4+wv] = sw; }
    __syncthreads();
    if (tid == 0) {
        const float p = red[0]*red[1]*red[2]*red[3];
        const float s = (red[4]+red[5]) + (red[6]+red[7]);
        const float v = 0.25f*(p+1.0f)*(p+1.0f)*(1.0f/(float)NF)
                      + 0.5f*s*(1.0f/((float)NF*(float)NT));
        atomicAdd(out, v);
    }
}

// ---------------- host ----------------
extern "C" void kernel_launch(void* const* d_in, const int* in_sizes, int n_in,
                              void* d_out, int out_size, void* d_ws, size_t ws_size,
                              hipStream_t stream)
{
    const float* A        = (const float*)d_in[0];
    const float* tau_init = (const float*)d_in[1];
    const float* GL_init  = (const float*)d_in[2];

    const size_t mat = (size_t)NF * NT;
    unsigned short* GLbf = (unsigned short*)d_ws;         // mat bf16
    unsigned short* mGh  = GLbf + mat;                    // mat bf16
    unsigned short* vGh  = mGh + mat;                     // mat bf16
    unsigned short* Abf  = vGh + mat;                     // mat bf16
    float* tau_g  = (float*)(Abf + mat);                  // 2*NALL
    float* mt_g   = tau_g  + 2*NALL;                      // 2*NALL
    float* vt_g   = mt_g   + 2*NALL;                      // 2*NALL
    float* Srow_g = vt_g   + 2*NALL;                      // 2*NALL
    float* Gcol   = Srow_g + 2*NALL;                      // NT
    float* Pcol   = Gcol   + NT;                          // NBLK*NT
    float* Pcol2  = Pcol + (size_t)NBLK * NT;             // SPLIT*NT (fallback)
    float* outp   = (float*)d_out;

    (void)hipMemsetAsync(d_out, 0, (size_t)out_size * sizeof(float), stream);
    castA_kernel<<<NF, TPB, 0, stream>>>(A, Abf);

    int dev = 0, coop = 0, numCU = 0, occ = 0;
    (void)hipGetDevice(&dev);
    (void)hipDeviceGetAttribute(&coop, hipDeviceAttributeCooperativeLaunch, dev);
    (void)hipDeviceGetAttribute(&numCU, hipDeviceAttributeMultiprocessorCount, dev);
    (void)hipOccupancyMaxActiveBlocksPerMultiprocessor(&occ, (const void*)mega_kernel, TPB, 0);

    if (coop && (long)occ * numCU >= NBLK) {
        void* args[] = {
            (void*)&A, (void*)&tau_init, (void*)&GL_init,
            (void*)&GLbf, (void*)&mGh, (void*)&vGh, (void*)&Abf,
            (void*)&tau_g, (void*)&mt_g, (void*)&vt_g,
            (void*)&Srow_g, (void*)&Pcol, (void*)&Gcol, (void*)&outp
        };
        (void)hipLaunchCooperativeKernel((void*)mega_kernel, dim3(NBLK), dim3(TPB),
                                         args, 0, stream);
    } else {
        float* tauw = tau_g;
        float* mt   = mt_g;
        float* vt   = vt_g;
        float* Srow = Srow_g;
        const dim3 csGrid(CGRP, SPLIT);
        for (int it = 1; it <= ITERS; ++it) {
            const float bc1i = (float)(1.0 / (1.0 - pow(0.9,   (double)it)));
            const float bc2i = (float)(1.0 / (1.0 - pow(0.999, (double)it)));
            if (it == 1) {
                step_kernel<true><<<NBLK, TPB, 0, stream>>>(GL_init, GLbf, mGh, vGh, Abf,
                                                            tau_init, Srow, Pcol, bc1i, bc2i);
                colsum_kernel<<<csGrid, TPB, 0, stream>>>(Pcol, Pcol2);
                tau_kernel<true><<<NALL/TPB, TPB, 0, stream>>>(tau_init, tauw, mt, vt,
                                                               Srow, Pcol2, bc1i, bc2i);
            } else {
                step_kernel<false><<<NBLK, TPB, 0, stream>>>(nullptr, GLbf, mGh, vGh, Abf,
                                                             tauw, Srow, Pcol, bc1i, bc2i);
                colsum_kernel<<<csGrid, TPB, 0, stream>>>(Pcol, Pcol2);
                tau_kernel<false><<<NALL/TPB, TPB, 0, stream>>>(nullptr, tauw, mt, vt,
                                                                Srow, Pcol2, bc1i, bc2i);
            }
        }
        loss_kernel<<<NF, TPB, 0, stream>>>(GLbf, A, tauw, (float*)d_out);
    }
}